// Round 1
// baseline (205.492 us; speedup 1.0000x reference)
//
#include <hip/hip_runtime.h>

#define SL 256
#define DMODEL 64

typedef _Float16 f16;
typedef _Float16 f16x8 __attribute__((ext_vector_type(8)));
typedef _Float16 f16x4 __attribute__((ext_vector_type(4)));
typedef float f32x4 __attribute__((ext_vector_type(4)));

#define PITCH 40  // f16 elements per LDS row (32 data + 8 pad); 80B rows keep 16B alignment, <=2-way banks

// ---------------------------------------------------------------------------
// Kernel A: implicit filter MLP  (one block per sequence position l)
//   h = sin(freq*(z@w1+b1)); h = sin(freq*(h@w2+b2)); h = sin(freq*(h@w3+b3));
//   hout[l][d] = (h@wo)[d] * exp(-t_l * |delta_d|)
// ---------------------------------------------------------------------------
__global__ __launch_bounds__(64) void k_filters(
    const float* __restrict__ z,
    const float* __restrict__ w1, const float* __restrict__ b1,
    const float* __restrict__ w2, const float* __restrict__ b2,
    const float* __restrict__ w3, const float* __restrict__ b3,
    const float* __restrict__ wo, const float* __restrict__ freq,
    float* __restrict__ hout)
{
    const int l = blockIdx.x;
    const int t = threadIdx.x;
    __shared__ float zb[33];
    __shared__ float ha[64];
    __shared__ float hb[64];

    if (t < 33) zb[t] = z[l * 33 + t];
    __syncthreads();

    const float fr = freq[t];
    float s = b1[t];
    for (int k = 0; k < 33; ++k) s += zb[k] * w1[k * 64 + t];
    ha[t] = sinf(fr * s);
    __syncthreads();

    s = b2[t];
    for (int k = 0; k < 64; ++k) s += ha[k] * w2[k * 64 + t];
    hb[t] = sinf(fr * s);
    __syncthreads();            // all reads of ha done

    s = b3[t];
    for (int k = 0; k < 64; ++k) s += hb[k] * w3[k * 64 + t];
    ha[t] = sinf(fr * s);       // safe: last ha reads were before previous barrier
    __syncthreads();

    s = 0.f;
    for (int k = 0; k < 64; ++k) s += ha[k] * wo[k * 64 + t];

    const float MIN_DEC = -3.0701134573253937f;   // log(0.01)/1.5
    const float MAX_DEC = -15.350567286626968f;   // log(0.01)/0.3
    float ad = fabsf(MIN_DEC + (MAX_DEC - MIN_DEC) * ((float)t / 63.0f));
    float tl = (float)l / 255.0f;
    hout[l * 64 + t] = s * expf(-tl * ad);
}

// ---------------------------------------------------------------------------
// R-copy builder: 8 shift-staggered copies of the reversed zero-padded filter
// column so every Toeplitz MFMA fragment is one aligned ds_read_b128.
//   Rfull[u] = (u<=255) ? h[255-u][d] : 0,  copy c: R[c*520+k] = Rfull[k+c]
// Fragment value T[row][k] = h[row-k] = Rfull[255-row+k]:
//   s0 = 255-row+k0+quad*8 ; c = s0&7 ; read f16x8 at R[c*520 + (s0-c)]
// ---------------------------------------------------------------------------
__device__ __forceinline__ void build_R(f16* R, const float* __restrict__ hcol,
                                        int d, int tid)
{
    for (int idx = tid; idx < 8 * 520; idx += 256) {
        int c = idx / 520;
        int k = idx - c * 520;
        int u = k + c;
        float v = (u <= 255) ? hcol[(255 - u) * 64 + d] : 0.f;
        R[idx] = (f16)v;
    }
}

// ---------------------------------------------------------------------------
// Stage 1: tmpT[b,d][j][p] = sum_{q<=j} x[b,d,p,q] * hy[j-q,d]   (f16 out)
// Block: 128 rows (p) x 256 cols (j), K=256. 4 waves, each 64x128.
// ---------------------------------------------------------------------------
__global__ __launch_bounds__(256, 2) void k_stage1(
    const float* __restrict__ x, const float* __restrict__ hy,
    f16* __restrict__ tmpT)
{
    const int pt = blockIdx.x;          // p half (0/1)
    const int bb = blockIdx.y;          // batch
    const int d  = blockIdx.z;          // channel
    const int tid  = threadIdx.x;
    const int lane = tid & 63;
    const int wave = tid >> 6;
    const int ln   = lane & 15;
    const int quad = lane >> 4;
    const int wm   = wave & 1;
    const int wn   = wave >> 1;

    __shared__ __align__(16) f16 As[128 * PITCH];
    __shared__ __align__(16) f16 R[8 * 520];

    build_R(R, hy, d, tid);

    const float* xbd = x + (size_t)(bb * 64 + d) * (SL * SL) + (size_t)pt * 128 * SL;

    f32x4 acc[4][8];
#pragma unroll
    for (int a = 0; a < 4; ++a)
#pragma unroll
        for (int c = 0; c < 8; ++c) acc[a][c] = (f32x4){0.f, 0.f, 0.f, 0.f};

    __syncthreads();   // R ready

    for (int q0 = 0; q0 < 256; q0 += 32) {
        // stage A tile: 128 x 32 fp32 -> f16
#pragma unroll
        for (int pass = 0; pass < 4; ++pass) {
            int flat = pass * 1024 + tid * 4;
            int row = flat >> 5;
            int col = flat & 31;
            float4 v = *(const float4*)(xbd + row * SL + q0 + col);
            f16x4 h;
            h[0] = (f16)v.x; h[1] = (f16)v.y; h[2] = (f16)v.z; h[3] = (f16)v.w;
            *(f16x4*)&As[row * PITCH + col] = h;
        }
        __syncthreads();

        f16x8 af[4], bfr[8];
#pragma unroll
        for (int rt = 0; rt < 4; ++rt)
            af[rt] = *(const f16x8*)&As[(wm * 64 + rt * 16 + ln) * PITCH + quad * 8];
#pragma unroll
        for (int ct = 0; ct < 8; ++ct) {
            int j = wn * 128 + ct * 16 + ln;
            int s0 = 255 - j + q0 + quad * 8;
            int c = s0 & 7;
            bfr[ct] = *(const f16x8*)&R[c * 520 + (s0 - c)];
        }
#pragma unroll
        for (int rt = 0; rt < 4; ++rt)
#pragma unroll
            for (int ct = 0; ct < 8; ++ct)
                acc[rt][ct] = __builtin_amdgcn_mfma_f32_16x16x32_f16(
                    af[rt], bfr[ct], acc[rt][ct], 0, 0, 0);
        __syncthreads();
    }

    // write transposed: tmpT[j][p], f16
    f16* tbd = tmpT + (size_t)(bb * 64 + d) * (SL * SL);
#pragma unroll
    for (int rt = 0; rt < 4; ++rt)
#pragma unroll
        for (int ct = 0; ct < 8; ++ct) {
            int j = wn * 128 + ct * 16 + ln;
            int p = pt * 128 + wm * 64 + rt * 16 + quad * 4;
            f16x4 v;
            v[0] = (f16)acc[rt][ct][0];
            v[1] = (f16)acc[rt][ct][1];
            v[2] = (f16)acc[rt][ct][2];
            v[3] = (f16)acc[rt][ct][3];
            *(f16x4*)&tbd[j * SL + p] = v;
        }
}

// ---------------------------------------------------------------------------
// Stage 2: out[b,d,i,j] = (sum_{p<=i} hx[i-p,d]*tmpT[j][p]) / 512 + x*bias[d]
// Block: 128 rows (i) x 256 cols (j), K=256 (p). A = Toeplitz(hx) via R.
// ---------------------------------------------------------------------------
__global__ __launch_bounds__(256, 2) void k_stage2(
    const float* __restrict__ x, const float* __restrict__ hx,
    const f16* __restrict__ tmpT, const float* __restrict__ bias,
    float* __restrict__ out)
{
    const int it = blockIdx.x;          // i half (0/1)
    const int bb = blockIdx.y;
    const int d  = blockIdx.z;
    const int tid  = threadIdx.x;
    const int lane = tid & 63;
    const int wave = tid >> 6;
    const int ln   = lane & 15;
    const int quad = lane >> 4;
    const int wm   = wave & 1;
    const int wn   = wave >> 1;

    __shared__ __align__(16) f16 Bs[256 * PITCH];
    __shared__ __align__(16) f16 R[8 * 520];

    build_R(R, hx, d, tid);

    const f16* tbd = tmpT + (size_t)(bb * 64 + d) * (SL * SL);

    f32x4 acc[4][8];
#pragma unroll
    for (int a = 0; a < 4; ++a)
#pragma unroll
        for (int c = 0; c < 8; ++c) acc[a][c] = (f32x4){0.f, 0.f, 0.f, 0.f};

    __syncthreads();   // R ready

    for (int p0 = 0; p0 < 256; p0 += 32) {
        // stage B tile: 256 rows (j) x 32 (k=p), f16 copy
        {
            int jr = tid >> 2;
            int c4 = tid & 3;
#pragma unroll
            for (int rep = 0; rep < 4; ++rep) {
                int j = rep * 64 + jr;
                f16x8 v = *(const f16x8*)&tbd[j * SL + p0 + c4 * 8];
                *(f16x8*)&Bs[j * PITCH + c4 * 8] = v;
            }
        }
        __syncthreads();

        f16x8 af[4], bfr[8];
#pragma unroll
        for (int rt = 0; rt < 4; ++rt) {
            int i = it * 128 + wm * 64 + rt * 16 + ln;
            int s0 = 255 - i + p0 + quad * 8;
            int c = s0 & 7;
            af[rt] = *(const f16x8*)&R[c * 520 + (s0 - c)];
        }
#pragma unroll
        for (int ct = 0; ct < 8; ++ct)
            bfr[ct] = *(const f16x8*)&Bs[(wn * 128 + ct * 16 + ln) * PITCH + quad * 8];
#pragma unroll
        for (int rt = 0; rt < 4; ++rt)
#pragma unroll
            for (int ct = 0; ct < 8; ++ct)
                acc[rt][ct] = __builtin_amdgcn_mfma_f32_16x16x32_f16(
                    af[rt], bfr[ct], acc[rt][ct], 0, 0, 0);
        __syncthreads();
    }

    // epilogue: /512 + x*bias
    const float bv = bias[d];
    const float* xbd = x + (size_t)(bb * 64 + d) * (SL * SL);
    float* obd = out + (size_t)(bb * 64 + d) * (SL * SL);
    const float sc = 1.0f / 512.0f;
#pragma unroll
    for (int rt = 0; rt < 4; ++rt)
#pragma unroll
        for (int ct = 0; ct < 8; ++ct) {
            int j = wn * 128 + ct * 16 + ln;
            int ib = it * 128 + wm * 64 + rt * 16 + quad * 4;
#pragma unroll
            for (int r = 0; r < 4; ++r) {
                int i = ib + r;
                obd[i * SL + j] = acc[rt][ct][r] * sc + xbd[i * SL + j] * bv;
            }
        }
}

extern "C" void kernel_launch(void* const* d_in, const int* in_sizes, int n_in,
                              void* d_out, int out_size, void* d_ws, size_t ws_size,
                              hipStream_t stream)
{
    (void)in_sizes; (void)n_in; (void)out_size; (void)ws_size;
    const float* x     = (const float*)d_in[0];
    const float* z     = (const float*)d_in[1];
    const float* Xw1   = (const float*)d_in[2];
    const float* Xb1   = (const float*)d_in[3];
    const float* Xw2   = (const float*)d_in[4];
    const float* Xb2   = (const float*)d_in[5];
    const float* Xw3   = (const float*)d_in[6];
    const float* Xb3   = (const float*)d_in[7];
    const float* Xwo   = (const float*)d_in[8];
    const float* Xfreq = (const float*)d_in[9];
    const float* Yw1   = (const float*)d_in[10];
    const float* Yb1   = (const float*)d_in[11];
    const float* Yw2   = (const float*)d_in[12];
    const float* Yb2   = (const float*)d_in[13];
    const float* Yw3   = (const float*)d_in[14];
    const float* Yb3   = (const float*)d_in[15];
    const float* Ywo   = (const float*)d_in[16];
    const float* Yfreq = (const float*)d_in[17];
    const float* bias  = (const float*)d_in[18];

    float* hx  = (float*)d_ws;                          // 256*64 f32
    float* hy  = hx + 256 * 64;                         // 256*64 f32
    f16*   tmpT = (f16*)((char*)d_ws + 2 * 256 * 64 * 4); // 4*64*256*256 f16 = 33.5 MB

    k_filters<<<256, 64, 0, stream>>>(z, Xw1, Xb1, Xw2, Xb2, Xw3, Xb3, Xwo, Xfreq, hx);
    k_filters<<<256, 64, 0, stream>>>(z, Yw1, Yb1, Yw2, Yb2, Yw3, Yb3, Ywo, Yfreq, hy);
    k_stage1<<<dim3(2, 4, 64), 256, 0, stream>>>(x, hy, tmpT);
    k_stage2<<<dim3(2, 4, 64), 256, 0, stream>>>(x, hx, tmpT, bias, (float*)d_out);
}

// Round 2
// 195.342 us; speedup vs baseline: 1.0520x; 1.0520x over previous
//
#include <hip/hip_runtime.h>

#define SL 256

typedef _Float16 f16;
typedef _Float16 f16x8 __attribute__((ext_vector_type(8)));
typedef _Float16 f16x4 __attribute__((ext_vector_type(4)));
typedef float f32x4 __attribute__((ext_vector_type(4)));

// ---------------------------------------------------------------------------
// Filter MLP: one block per (l, sel); sel=0 -> hx (X params), sel=1 -> hy.
// ---------------------------------------------------------------------------
__global__ __launch_bounds__(64) void k_filters(
    const float* __restrict__ z,
    const float* __restrict__ Xw1, const float* __restrict__ Xb1,
    const float* __restrict__ Xw2, const float* __restrict__ Xb2,
    const float* __restrict__ Xw3, const float* __restrict__ Xb3,
    const float* __restrict__ Xwo, const float* __restrict__ Xfreq,
    const float* __restrict__ Yw1, const float* __restrict__ Yb1,
    const float* __restrict__ Yw2, const float* __restrict__ Yb2,
    const float* __restrict__ Yw3, const float* __restrict__ Yb3,
    const float* __restrict__ Ywo, const float* __restrict__ Yfreq,
    float* __restrict__ hx, float* __restrict__ hy)
{
    const int l = blockIdx.x;
    const int sel = blockIdx.y;
    const int t = threadIdx.x;
    const float* w1 = sel ? Yw1 : Xw1;  const float* b1 = sel ? Yb1 : Xb1;
    const float* w2 = sel ? Yw2 : Xw2;  const float* b2 = sel ? Yb2 : Xb2;
    const float* w3 = sel ? Yw3 : Xw3;  const float* b3 = sel ? Yb3 : Xb3;
    const float* wo = sel ? Ywo : Xwo;  const float* freq = sel ? Yfreq : Xfreq;
    float* hout = sel ? hy : hx;

    __shared__ float zb[33];
    __shared__ float ha[64];
    __shared__ float hb[64];

    if (t < 33) zb[t] = z[l * 33 + t];
    __syncthreads();

    const float fr = freq[t];
    float s = b1[t];
    for (int k = 0; k < 33; ++k) s += zb[k] * w1[k * 64 + t];
    ha[t] = sinf(fr * s);
    __syncthreads();

    s = b2[t];
    for (int k = 0; k < 64; ++k) s += ha[k] * w2[k * 64 + t];
    hb[t] = sinf(fr * s);
    __syncthreads();

    s = b3[t];
    for (int k = 0; k < 64; ++k) s += hb[k] * w3[k * 64 + t];
    ha[t] = sinf(fr * s);
    __syncthreads();

    s = 0.f;
    for (int k = 0; k < 64; ++k) s += ha[k] * wo[k * 64 + t];

    const float MIN_DEC = -3.0701134573253937f;   // log(0.01)/1.5
    const float MAX_DEC = -15.350567286626968f;   // log(0.01)/0.3
    float ad = fabsf(MIN_DEC + (MAX_DEC - MIN_DEC) * ((float)t / 63.0f));
    float tl = (float)l / 255.0f;
    hout[l * 64 + t] = s * expf(-tl * ad);
}

// ---------------------------------------------------------------------------
// R-copy Toeplitz table: 8 shift-staggered copies of reversed zero-padded
// filter column so every Toeplitz fragment is one aligned ds_read_b128.
//   Rfull[u] = (u<=255) ? h[255-u][d] : 0 ;  R[c*520+k] = Rfull[k+c]
// Fragment T[row][k] = h[row-k] = Rfull[255-row+k]:
//   s0 = 255-row+k0+quad*8 ; c = s0&7 ; f16x8 at R[c*520 + (s0-c)]
// ---------------------------------------------------------------------------
__device__ __forceinline__ void build_R(f16* R, const float* __restrict__ hcol,
                                        int d, int tid)
{
    for (int idx = tid; idx < 8 * 520; idx += 512) {
        int c = idx / 520;
        int k = idx - c * 520;
        int u = k + c;
        float v = (u <= 255) ? hcol[(255 - u) * 64 + d] : 0.f;
        R[idx] = (f16)v;
    }
}

// ---------------------------------------------------------------------------
// Fused: one block per (b,d). Phase 1: M[p][j] = sum_q x[p][q]*hy[j-q] into
// LDS (f16, XOR-swizzled). Phase 2: out[i][j] = (sum_p hx[i-p]*M[p][j])/512
// + x[i][j]*bias[d]. 512 threads = 8 waves; tmp resident -> phase 2 has no
// barriers; phase 1 loads x direct to registers -> no barriers either.
// ---------------------------------------------------------------------------
__global__ __launch_bounds__(512, 2) void k_fused(
    const float* __restrict__ x, const float* __restrict__ hx,
    const float* __restrict__ hy, const float* __restrict__ bias,
    float* __restrict__ out)
{
    const int bd = blockIdx.x;          // b*64 + d
    const int d  = bd & 63;
    const int tid  = threadIdx.x;
    const int lane = tid & 63;
    const int wave = tid >> 6;
    const int ln   = lane & 15;
    const int quad = lane >> 4;

    __shared__ __align__(16) f16 tmp[256 * 256];   // 131072 B, [j][p^msk(j)]
    __shared__ __align__(16) f16 R[8 * 520];       // 8320 B

    const float* xbd = x + (size_t)bd * (SL * SL);

    build_R(R, hy, d, tid);

    f32x4 acc[32];
#pragma unroll
    for (int a = 0; a < 32; ++a) acc[a] = (f32x4){0.f, 0.f, 0.f, 0.f};

    __syncthreads();   // R(hy) ready

    // ---------------- Phase 1: waves = 4(p) x 2(j), tile 64p x 128j --------
    {
        const int wp = wave & 3;
        const int wj = wave >> 2;
        for (int q0 = 0; q0 < 256; q0 += 32) {
            f16x8 af[4], bf[8];
#pragma unroll
            for (int rt = 0; rt < 4; ++rt) {
                int p = wp * 64 + rt * 16 + ln;
                const float* src = xbd + p * SL + q0 + quad * 8;
                float4 v0 = *(const float4*)src;
                float4 v1 = *(const float4*)(src + 4);
                f16x8 h;
                h[0] = (f16)v0.x; h[1] = (f16)v0.y; h[2] = (f16)v0.z; h[3] = (f16)v0.w;
                h[4] = (f16)v1.x; h[5] = (f16)v1.y; h[6] = (f16)v1.z; h[7] = (f16)v1.w;
                af[rt] = h;
            }
#pragma unroll
            for (int ct = 0; ct < 8; ++ct) {
                int j = wj * 128 + ct * 16 + ln;
                int s0 = 255 - j + q0 + quad * 8;
                int c = s0 & 7;
                bf[ct] = *(const f16x8*)&R[c * 520 + (s0 - c)];
            }
#pragma unroll
            for (int rt = 0; rt < 4; ++rt)
#pragma unroll
                for (int ct = 0; ct < 8; ++ct)
                    acc[rt * 8 + ct] = __builtin_amdgcn_mfma_f32_16x16x32_f16(
                        af[rt], bf[ct], acc[rt * 8 + ct], 0, 0, 0);
        }

        // write M to LDS: element (j,p) at tmp[j*256 + (p ^ ((j&7)<<3))]
#pragma unroll
        for (int rt = 0; rt < 4; ++rt)
#pragma unroll
            for (int ct = 0; ct < 8; ++ct) {
                int j = wj * 128 + ct * 16 + ln;
                int pb = wp * 64 + rt * 16 + quad * 4;
                f32x4 a = acc[rt * 8 + ct];
                f16x4 v;
                v[0] = (f16)a[0]; v[1] = (f16)a[1];
                v[2] = (f16)a[2]; v[3] = (f16)a[3];
                *(f16x4*)&tmp[j * 256 + (pb ^ ((j & 7) << 3))] = v;
            }
    }

    __syncthreads();   // tmp complete, R(hy) reads done
    build_R(R, hx, d, tid);
#pragma unroll
    for (int a = 0; a < 32; ++a) acc[a] = (f32x4){0.f, 0.f, 0.f, 0.f};
    __syncthreads();   // R(hx) ready

    // ---------------- Phase 2: waves = 2(i) x 4(j), tile 128i x 64j --------
    const int wi  = wave & 1;
    const int wj2 = wave >> 1;
    for (int p0 = 0; p0 < 256; p0 += 32) {
        f16x8 af[8], bf[4];
#pragma unroll
        for (int rt = 0; rt < 8; ++rt) {
            int i = wi * 128 + rt * 16 + ln;
            int s0 = 255 - i + p0 + quad * 8;
            int c = s0 & 7;
            af[rt] = *(const f16x8*)&R[c * 520 + (s0 - c)];
        }
#pragma unroll
        for (int ct = 0; ct < 4; ++ct) {
            int j = wj2 * 64 + ct * 16 + ln;
            int off = (p0 + quad * 8) ^ ((j & 7) << 3);
            bf[ct] = *(const f16x8*)&tmp[j * 256 + off];
        }
#pragma unroll
        for (int rt = 0; rt < 8; ++rt)
#pragma unroll
            for (int ct = 0; ct < 4; ++ct)
                acc[rt * 4 + ct] = __builtin_amdgcn_mfma_f32_16x16x32_f16(
                    af[rt], bf[ct], acc[rt * 4 + ct], 0, 0, 0);
    }

    // epilogue: /512 + x*bias
    const float bv = bias[d];
    const float sc = 1.0f / 512.0f;
    float* obd = out + (size_t)bd * (SL * SL);
#pragma unroll
    for (int rt = 0; rt < 8; ++rt)
#pragma unroll
        for (int ct = 0; ct < 4; ++ct) {
            int j  = wj2 * 64 + ct * 16 + ln;
            int ib = wi * 128 + rt * 16 + quad * 4;
            f32x4 a = acc[rt * 4 + ct];
#pragma unroll
            for (int r = 0; r < 4; ++r) {
                int i = ib + r;
                obd[i * SL + j] = a[r] * sc + xbd[i * SL + j] * bv;
            }
        }
}

extern "C" void kernel_launch(void* const* d_in, const int* in_sizes, int n_in,
                              void* d_out, int out_size, void* d_ws, size_t ws_size,
                              hipStream_t stream)
{
    (void)in_sizes; (void)n_in; (void)out_size; (void)ws_size;
    const float* x     = (const float*)d_in[0];
    const float* z     = (const float*)d_in[1];
    const float* Xw1   = (const float*)d_in[2];
    const float* Xb1   = (const float*)d_in[3];
    const float* Xw2   = (const float*)d_in[4];
    const float* Xb2   = (const float*)d_in[5];
    const float* Xw3   = (const float*)d_in[6];
    const float* Xb3   = (const float*)d_in[7];
    const float* Xwo   = (const float*)d_in[8];
    const float* Xfreq = (const float*)d_in[9];
    const float* Yw1   = (const float*)d_in[10];
    const float* Yb1   = (const float*)d_in[11];
    const float* Yw2   = (const float*)d_in[12];
    const float* Yb2   = (const float*)d_in[13];
    const float* Yw3   = (const float*)d_in[14];
    const float* Yb3   = (const float*)d_in[15];
    const float* Ywo   = (const float*)d_in[16];
    const float* Yfreq = (const float*)d_in[17];
    const float* bias  = (const float*)d_in[18];

    float* hx = (float*)d_ws;              // 256*64 f32
    float* hy = hx + 256 * 64;             // 256*64 f32

    k_filters<<<dim3(256, 2), 64, 0, stream>>>(
        z, Xw1, Xb1, Xw2, Xb2, Xw3, Xb3, Xwo, Xfreq,
        Yw1, Yb1, Yw2, Yb2, Yw3, Yb3, Ywo, Yfreq, hx, hy);
    k_fused<<<256, 512, 0, stream>>>(x, hx, hy, bias, (float*)d_out);
}

// Round 3
// 192.444 us; speedup vs baseline: 1.0678x; 1.0151x over previous
//
#include <hip/hip_runtime.h>

#define SL 256

typedef _Float16 f16;
typedef _Float16 f16x8 __attribute__((ext_vector_type(8)));
typedef _Float16 f16x4 __attribute__((ext_vector_type(4)));
typedef float f32x4 __attribute__((ext_vector_type(4)));

// ---------------------------------------------------------------------------
// Filter MLP: one block per (l, sel); sel=0 -> hx (X params), sel=1 -> hy.
// ---------------------------------------------------------------------------
__global__ __launch_bounds__(64) void k_filters(
    const float* __restrict__ z,
    const float* __restrict__ Xw1, const float* __restrict__ Xb1,
    const float* __restrict__ Xw2, const float* __restrict__ Xb2,
    const float* __restrict__ Xw3, const float* __restrict__ Xb3,
    const float* __restrict__ Xwo, const float* __restrict__ Xfreq,
    const float* __restrict__ Yw1, const float* __restrict__ Yb1,
    const float* __restrict__ Yw2, const float* __restrict__ Yb2,
    const float* __restrict__ Yw3, const float* __restrict__ Yb3,
    const float* __restrict__ Ywo, const float* __restrict__ Yfreq,
    float* __restrict__ hx, float* __restrict__ hy)
{
    const int l = blockIdx.x;
    const int sel = blockIdx.y;
    const int t = threadIdx.x;
    const float* w1 = sel ? Yw1 : Xw1;  const float* b1 = sel ? Yb1 : Xb1;
    const float* w2 = sel ? Yw2 : Xw2;  const float* b2 = sel ? Yb2 : Xb2;
    const float* w3 = sel ? Yw3 : Xw3;  const float* b3 = sel ? Yb3 : Xb3;
    const float* wo = sel ? Ywo : Xwo;  const float* freq = sel ? Yfreq : Xfreq;
    float* hout = sel ? hy : hx;

    __shared__ float zb[33];
    __shared__ float ha[64];
    __shared__ float hb[64];

    if (t < 33) zb[t] = z[l * 33 + t];
    __syncthreads();

    const float fr = freq[t];
    float s = b1[t];
    for (int k = 0; k < 33; ++k) s += zb[k] * w1[k * 64 + t];
    ha[t] = sinf(fr * s);
    __syncthreads();

    s = b2[t];
    for (int k = 0; k < 64; ++k) s += ha[k] * w2[k * 64 + t];
    hb[t] = sinf(fr * s);
    __syncthreads();

    s = b3[t];
    for (int k = 0; k < 64; ++k) s += hb[k] * w3[k * 64 + t];
    ha[t] = sinf(fr * s);
    __syncthreads();

    s = 0.f;
    for (int k = 0; k < 64; ++k) s += ha[k] * wo[k * 64 + t];

    const float MIN_DEC = -3.0701134573253937f;   // log(0.01)/1.5
    const float MAX_DEC = -15.350567286626968f;   // log(0.01)/0.3
    float ad = fabsf(MIN_DEC + (MAX_DEC - MIN_DEC) * ((float)t / 63.0f));
    float tl = (float)l / 255.0f;
    hout[l * 64 + t] = s * expf(-tl * ad);
}

// ---------------------------------------------------------------------------
// R-copy Toeplitz table: 8 shift-staggered copies of reversed zero-padded
// filter column so every Toeplitz fragment is one aligned ds_read_b128.
//   Rfull[u] = (u<=255) ? h[255-u][d] : 0 ;  R[c*520+k] = Rfull[k+c]
// Fragment T[row][k] = h[row-k] = Rfull[255-row+k]:
//   s0 = 255-row+k0+quad*8 ; c = s0&7 ; f16x8 at R[c*520 + (s0-c)]
// ---------------------------------------------------------------------------
__device__ __forceinline__ void build_R(f16* R, const float* __restrict__ hcol,
                                        int d, int tid)
{
    for (int idx = tid; idx < 8 * 520; idx += 1024) {
        int c = idx / 520;
        int k = idx - c * 520;
        int u = k + c;
        float v = (u <= 255) ? hcol[(255 - u) * 64 + d] : 0.f;
        R[idx] = (f16)v;
    }
}

// ---------------------------------------------------------------------------
// Fused, 1024 threads (16 waves, 4/SIMD): one block per (b,d).
// Phase 1: M[p][j] = sum_q x[p][q]*hy[j-q] -> LDS tmp (f16, XOR swizzle).
// Phase 2: D[j][i] = sum_p tmp[j][p]*hx[i-p]  (A=tmp, B=Toeplitz(hx)) so the
//          C fragment holds 4 consecutive j per lane -> float4 epilogue:
//          out[i][j..j+3] = D/512 + x*bias.
// Only 3 barriers total; phases are barrier-free internally.
// ---------------------------------------------------------------------------
__global__ __launch_bounds__(1024, 4) void k_fused(
    const float* __restrict__ x, const float* __restrict__ hx,
    const float* __restrict__ hy, const float* __restrict__ bias,
    float* __restrict__ out)
{
    const int bd = blockIdx.x;          // b*64 + d
    const int d  = bd & 63;
    const int tid  = threadIdx.x;
    const int lane = tid & 63;
    const int wave = tid >> 6;
    const int ln   = lane & 15;
    const int quad = lane >> 4;

    __shared__ __align__(16) f16 tmp[256 * 256];   // [j][p ^ ((j&7)<<3)]
    __shared__ __align__(16) f16 R[8 * 520];

    const float* xbd = x + (size_t)bd * (SL * SL);

    build_R(R, hy, d, tid);

    f32x4 acc[16];
#pragma unroll
    for (int a = 0; a < 16; ++a) acc[a] = (f32x4){0.f, 0.f, 0.f, 0.f};

    __syncthreads();   // R(hy) ready

    // ---------------- Phase 1: waves = 4(p) x 4(j), tile 64p x 64j ---------
    {
        const int wp = wave & 3;
        const int wj = wave >> 2;

        // prefetch first x tile
        float4 pv0[4], pv1[4];
#pragma unroll
        for (int rt = 0; rt < 4; ++rt) {
            const float* src = xbd + (wp * 64 + rt * 16 + ln) * SL + quad * 8;
            pv0[rt] = *(const float4*)src;
            pv1[rt] = *(const float4*)(src + 4);
        }

        for (int q0 = 0; q0 < 256; q0 += 32) {
            f16x8 af[4], bf[4];
#pragma unroll
            for (int rt = 0; rt < 4; ++rt) {
                f16x8 h;
                h[0] = (f16)pv0[rt].x; h[1] = (f16)pv0[rt].y;
                h[2] = (f16)pv0[rt].z; h[3] = (f16)pv0[rt].w;
                h[4] = (f16)pv1[rt].x; h[5] = (f16)pv1[rt].y;
                h[6] = (f16)pv1[rt].z; h[7] = (f16)pv1[rt].w;
                af[rt] = h;
            }
            if (q0 < 224) {
#pragma unroll
                for (int rt = 0; rt < 4; ++rt) {
                    const float* src = xbd + (wp * 64 + rt * 16 + ln) * SL
                                     + q0 + 32 + quad * 8;
                    pv0[rt] = *(const float4*)src;
                    pv1[rt] = *(const float4*)(src + 4);
                }
            }
#pragma unroll
            for (int ct = 0; ct < 4; ++ct) {
                int j = wj * 64 + ct * 16 + ln;
                int s0 = 255 - j + q0 + quad * 8;
                int c = s0 & 7;
                bf[ct] = *(const f16x8*)&R[c * 520 + (s0 - c)];
            }
#pragma unroll
            for (int rt = 0; rt < 4; ++rt)
#pragma unroll
                for (int ct = 0; ct < 4; ++ct)
                    acc[rt * 4 + ct] = __builtin_amdgcn_mfma_f32_16x16x32_f16(
                        af[rt], bf[ct], acc[rt * 4 + ct], 0, 0, 0);
        }

        // write M to LDS: element (j,p) at tmp[j*256 + (p ^ ((j&7)<<3))]
#pragma unroll
        for (int rt = 0; rt < 4; ++rt)
#pragma unroll
            for (int ct = 0; ct < 4; ++ct) {
                int j = wj * 64 + ct * 16 + ln;
                int pb = wp * 64 + rt * 16 + quad * 4;
                f32x4 a = acc[rt * 4 + ct];
                f16x4 v;
                v[0] = (f16)a[0]; v[1] = (f16)a[1];
                v[2] = (f16)a[2]; v[3] = (f16)a[3];
                *(f16x4*)&tmp[j * 256 + (pb ^ ((j & 7) << 3))] = v;
            }
    }

    __syncthreads();   // tmp complete, R(hy) reads done
    build_R(R, hx, d, tid);
#pragma unroll
    for (int a = 0; a < 16; ++a) acc[a] = (f32x4){0.f, 0.f, 0.f, 0.f};
    __syncthreads();   // R(hx) ready

    // ---------------- Phase 2: D[j][i], waves = 4(i) x 4(j), 64i x 64j -----
    const int wii = wave & 3;
    const int wjj = wave >> 2;
    for (int p0 = 0; p0 < 256; p0 += 32) {
        f16x8 af[4], bf[4];
#pragma unroll
        for (int rt = 0; rt < 4; ++rt) {          // A = tmp[j][p]
            int j = wjj * 64 + rt * 16 + ln;
            int off = (p0 + quad * 8) ^ ((j & 7) << 3);
            af[rt] = *(const f16x8*)&tmp[j * 256 + off];
        }
#pragma unroll
        for (int ct = 0; ct < 4; ++ct) {          // B[p][i] = hx[i-p]
            int i = wii * 64 + ct * 16 + ln;
            int s0 = 255 - i + p0 + quad * 8;
            int c = s0 & 7;
            bf[ct] = *(const f16x8*)&R[c * 520 + (s0 - c)];
        }
#pragma unroll
        for (int rt = 0; rt < 4; ++rt)
#pragma unroll
            for (int ct = 0; ct < 4; ++ct)
                acc[rt * 4 + ct] = __builtin_amdgcn_mfma_f32_16x16x32_f16(
                    af[rt], bf[ct], acc[rt * 4 + ct], 0, 0, 0);
    }

    // epilogue: out[i][jb..jb+3] = acc/512 + x*bias  (float4, coalesced)
    const float bv = bias[d];
    const float sc = 1.0f / 512.0f;
    float* obd = out + (size_t)bd * (SL * SL);
#pragma unroll
    for (int rt = 0; rt < 4; ++rt)
#pragma unroll
        for (int ct = 0; ct < 4; ++ct) {
            int i  = wii * 64 + ct * 16 + ln;          // D col -> out row
            int jb = wjj * 64 + rt * 16 + quad * 4;    // D rows -> 4 consec j
            f32x4 a = acc[rt * 4 + ct];
            float4 xv = *(const float4*)(xbd + i * SL + jb);
            float4 o;
            o.x = a[0] * sc + xv.x * bv;
            o.y = a[1] * sc + xv.y * bv;
            o.z = a[2] * sc + xv.z * bv;
            o.w = a[3] * sc + xv.w * bv;
            *(float4*)(obd + i * SL + jb) = o;
        }
}

extern "C" void kernel_launch(void* const* d_in, const int* in_sizes, int n_in,
                              void* d_out, int out_size, void* d_ws, size_t ws_size,
                              hipStream_t stream)
{
    (void)in_sizes; (void)n_in; (void)out_size; (void)ws_size;
    const float* x     = (const float*)d_in[0];
    const float* z     = (const float*)d_in[1];
    const float* Xw1   = (const float*)d_in[2];
    const float* Xb1   = (const float*)d_in[3];
    const float* Xw2   = (const float*)d_in[4];
    const float* Xb2   = (const float*)d_in[5];
    const float* Xw3   = (const float*)d_in[6];
    const float* Xb3   = (const float*)d_in[7];
    const float* Xwo   = (const float*)d_in[8];
    const float* Xfreq = (const float*)d_in[9];
    const float* Yw1   = (const float*)d_in[10];
    const float* Yb1   = (const float*)d_in[11];
    const float* Yw2   = (const float*)d_in[12];
    const float* Yb2   = (const float*)d_in[13];
    const float* Yw3   = (const float*)d_in[14];
    const float* Yb3   = (const float*)d_in[15];
    const float* Ywo   = (const float*)d_in[16];
    const float* Yfreq = (const float*)d_in[17];
    const float* bias  = (const float*)d_in[18];

    float* hx = (float*)d_ws;              // 256*64 f32
    float* hy = hx + 256 * 64;             // 256*64 f32

    k_filters<<<dim3(256, 2), 64, 0, stream>>>(
        z, Xw1, Xb1, Xw2, Xb2, Xw3, Xb3, Xwo, Xfreq,
        Yw1, Yb1, Yw2, Yb2, Yw3, Yb3, Ywo, Yfreq, hx, hy);
    k_fused<<<256, 1024, 0, stream>>>(x, hx, hy, bias, (float*)d_out);
}